// Round 11
// baseline (286.209 us; speedup 1.0000x reference)
//
#include <hip/hip_runtime.h>
#include <hip/hip_bf16.h>
#include <math.h>

#define S_LEN 2048
#define HID_DIM 2048
#define NH 16
#define NKV 4
#define HD 128

typedef __attribute__((ext_vector_type(8))) short bf16x8;
typedef __attribute__((ext_vector_type(4))) float f32x4;

#define AS1 __attribute__((address_space(1)))
#define AS3 __attribute__((address_space(3)))

__device__ inline unsigned short f2bf(float f) {
  unsigned int u = __float_as_uint(f);
  unsigned int r = u + 0x7FFFu + ((u >> 16) & 1u);
  return (unsigned short)(r >> 16);
}
__device__ inline float bf2f(unsigned short u) {
  return __uint_as_float(((unsigned int)u) << 16);
}

// ---------------- weight transposes + hidden f32->bf16, one dispatch ----------
// z=0..3: transpose Wq/Wk/Wv/Wo into WT/WoT. z=4: hidden f32 -> bf16 copy.
__global__ __launch_bounds__(256) void transpose_all(
    const float* __restrict__ Wq, const float* __restrict__ Wk,
    const float* __restrict__ Wv, const float* __restrict__ Wo,
    unsigned short* __restrict__ WT, unsigned short* __restrict__ WoT,
    const float* __restrict__ hidden, unsigned short* __restrict__ h_bf)
{
  const int z = blockIdx.z;
  if (z == 4) {
    int bb = blockIdx.y * 64 + blockIdx.x;           // 0..4095
    int t = threadIdx.y * 32 + threadIdx.x;          // 0..255
    int i = (bb * 256 + t) * 4;
    float4 v = *(const float4*)&hidden[i];
    ushort4 o;
    o.x = f2bf(v.x); o.y = f2bf(v.y); o.z = f2bf(v.z); o.w = f2bf(v.w);
    *(ushort4*)&h_bf[i] = o;
    return;
  }
  __shared__ float t[32][33];
  const float* W; unsigned short* D; int N;
  if (z == 0)      { W = Wq; D = WT;                          N = 2048; }
  else if (z == 1) { W = Wk; D = WT + (size_t)2048 * 2048;    N = 512;  }
  else if (z == 2) { W = Wv; D = WT + (size_t)2560 * 2048;    N = 512;  }
  else             { W = Wo; D = WoT;                         N = 2048; }
  int bx = blockIdx.x * 32;
  if (bx >= N) return;
  int by = blockIdx.y * 32;
  int tx = threadIdx.x, ty = threadIdx.y;
  #pragma unroll
  for (int i = 0; i < 32; i += 8)
    t[ty + i][tx] = W[(size_t)(by + ty + i) * N + bx + tx];
  __syncthreads();
  #pragma unroll
  for (int i = 0; i < 32; i += 8)
    D[(size_t)(bx + ty + i) * 2048 + by + tx] = f2bf(t[tx][ty + i]);
}

// ---------------- 256x256 8-phase split-K GEMM (T3+T4+T5 template) ----------
// If outF != nullptr: epilogue atomically accumulates f32 into outF (pre-zeroed)
// instead of writing bf16 partials -> removes the separate add pass.
__global__ __launch_bounds__(512) void gemm_bt_8phase(
    const unsigned short* __restrict__ A,
    const unsigned short* __restrict__ Bt,
    unsigned short* __restrict__ P,   // [ksplit][M][N] bf16 partials (if !outF)
    float* __restrict__ outF,         // f32 accumulation target (or nullptr)
    int M, int N, int KF, int ksplit)
{
  extern __shared__ unsigned short smem[];
  unsigned short* Ab = smem;            // [2 buf][2 kh][256*32] = 32768 ush
  unsigned short* Bb = smem + 32768;    // same
  const int bm = blockIdx.y * 256, bn = blockIdx.x * 256, z = blockIdx.z;
  const int Kh = KF / ksplit, k0z = z * Kh;
  const int NT = Kh >> 6;               // K-tiles of 64
  const int tid = threadIdx.x, lane = tid & 63, wave = tid >> 6;
  const int wm = wave >> 2, wn = wave & 3;
  const int quad = lane >> 4, lcol = lane & 15;

  auto stageA = [&](int t, int kh) {
    const unsigned short* src = A + (size_t)bm * KF + k0z + t * 64 + kh * 32;
    unsigned short* dst = Ab + (((t & 1) * 2 + kh) << 13);
    #pragma unroll
    for (int i = 0; i < 2; i++) {
      int s = i * 512 + tid;
      int row = s >> 2, dc = s & 3, g = dc ^ ((row >> 1) & 3);
      __builtin_amdgcn_global_load_lds(
          (const AS1 void*)(src + (size_t)row * KF + g * 8),
          (AS3 void*)(dst + s * 8), 16, 0, 0);
    }
  };
  auto stageB = [&](int t, int kh) {
    const unsigned short* src = Bt + (size_t)bn * KF + k0z + t * 64 + kh * 32;
    unsigned short* dst = Bb + (((t & 1) * 2 + kh) << 13);
    #pragma unroll
    for (int i = 0; i < 2; i++) {
      int s = i * 512 + tid;
      int row = s >> 2, dc = s & 3, g = dc ^ ((row >> 1) & 3);
      __builtin_amdgcn_global_load_lds(
          (const AS1 void*)(src + (size_t)row * KF + g * 8),
          (AS3 void*)(dst + s * 8), 16, 0, 0);
    }
  };
  auto ldA = [&](int cur, int kh, int mh, bf16x8* af) {
    const unsigned short* base = Ab + ((cur * 2 + kh) << 13);
    #pragma unroll
    for (int m = 0; m < 4; m++) {
      int row = wm * 128 + (mh * 4 + m) * 16 + lcol;
      int ch = quad ^ ((row >> 1) & 3);
      af[m] = *(const bf16x8*)&base[row * 32 + ch * 8];
    }
  };
  auto ldB = [&](int cur, int kh, bf16x8* bfr) {
    const unsigned short* base = Bb + ((cur * 2 + kh) << 13);
    #pragma unroll
    for (int n = 0; n < 4; n++) {
      int row = wn * 64 + n * 16 + lcol;
      int ch = quad ^ ((row >> 1) & 3);
      bfr[n] = *(const bf16x8*)&base[row * 32 + ch * 8];
    }
  };

  f32x4 zero = {0.f, 0.f, 0.f, 0.f};
  f32x4 acc[8][4];
  #pragma unroll
  for (int i = 0; i < 8; i++)
    #pragma unroll
    for (int j = 0; j < 4; j++) acc[i][j] = zero;

  stageA(0, 0); stageB(0, 0); stageA(0, 1); stageB(0, 1);
  if (NT > 1) { stageA(1, 0); stageB(1, 0); }
  asm volatile("s_waitcnt vmcnt(8)" ::: "memory");
  __builtin_amdgcn_s_barrier();

  for (int t = 0; t < NT; t++) {
    const int cur = t & 1;
    bf16x8 af[4], bfr[4];
    // ---- p0: kh0, mh0 ----
    ldB(cur, 0, bfr);
    ldA(cur, 0, 0, af);
    __builtin_amdgcn_s_barrier();
    if (t + 1 < NT) stageA(t + 1, 1);
    __builtin_amdgcn_s_setprio(1);
    #pragma unroll
    for (int m = 0; m < 4; m++)
      #pragma unroll
      for (int n = 0; n < 4; n++)
        acc[m][n] = __builtin_amdgcn_mfma_f32_16x16x32_bf16(af[m], bfr[n], acc[m][n], 0, 0, 0);
    __builtin_amdgcn_s_setprio(0);
    // ---- p1: kh0, mh1 ----
    ldA(cur, 0, 1, af);
    asm volatile("s_waitcnt vmcnt(6)" ::: "memory");
    __builtin_amdgcn_s_barrier();
    if (t + 1 < NT) stageB(t + 1, 1);
    __builtin_amdgcn_s_setprio(1);
    #pragma unroll
    for (int m = 0; m < 4; m++)
      #pragma unroll
      for (int n = 0; n < 4; n++)
        acc[4 + m][n] = __builtin_amdgcn_mfma_f32_16x16x32_bf16(af[m], bfr[n], acc[4 + m][n], 0, 0, 0);
    __builtin_amdgcn_s_setprio(0);
    // ---- p2: kh1, mh0 ----
    ldB(cur, 1, bfr);
    ldA(cur, 1, 0, af);
    __builtin_amdgcn_s_barrier();
    if (t + 2 < NT) stageA(t + 2, 0);
    __builtin_amdgcn_s_setprio(1);
    #pragma unroll
    for (int m = 0; m < 4; m++)
      #pragma unroll
      for (int n = 0; n < 4; n++)
        acc[m][n] = __builtin_amdgcn_mfma_f32_16x16x32_bf16(af[m], bfr[n], acc[m][n], 0, 0, 0);
    __builtin_amdgcn_s_setprio(0);
    // ---- p3: kh1, mh1 ----
    ldA(cur, 1, 1, af);
    asm volatile("s_waitcnt vmcnt(6)" ::: "memory");
    __builtin_amdgcn_s_barrier();
    if (t + 2 < NT) stageB(t + 2, 0);
    __builtin_amdgcn_s_setprio(1);
    #pragma unroll
    for (int m = 0; m < 4; m++)
      #pragma unroll
      for (int n = 0; n < 4; n++)
        acc[4 + m][n] = __builtin_amdgcn_mfma_f32_16x16x32_bf16(af[m], bfr[n], acc[4 + m][n], 0, 0, 0);
    __builtin_amdgcn_s_setprio(0);
  }

  if (outF) {
    // fused f32 accumulation (out pre-zeroed; each address hit ksplit times)
    #pragma unroll
    for (int mr = 0; mr < 8; mr++)
      #pragma unroll
      for (int nr = 0; nr < 4; nr++)
        #pragma unroll
        for (int r = 0; r < 4; r++) {
          int mm = bm + wm * 128 + mr * 16 + quad * 4 + r;
          int nn = bn + wn * 64 + nr * 16 + lcol;
          atomicAdd(&outF[(size_t)mm * N + nn], acc[mr][nr][r]);
        }
  } else {
    unsigned short* Pz = P + (size_t)z * M * N;
    #pragma unroll
    for (int mr = 0; mr < 8; mr++)
      #pragma unroll
      for (int nr = 0; nr < 4; nr++)
        #pragma unroll
        for (int r = 0; r < 4; r++) {
          int mm = bm + wm * 128 + mr * 16 + quad * 4 + r;
          int nn = bn + wn * 64 + nr * 16 + lcol;
          Pz[(size_t)mm * N + nn] = f2bf(acc[mr][nr][r]);
        }
  }
}

// ---------------- fused RoPE + V-prep (one dispatch) ----------------
__global__ __launch_bounds__(256) void rope_prepv_kernel(
    const unsigned short* __restrict__ P0,  // [S][3072] bf16
    const unsigned short* __restrict__ P1,
    const int* __restrict__ positions,
    unsigned short* __restrict__ q_ws,   // [NH][S][HD]  (scaled!)
    unsigned short* __restrict__ k_ws,   // [NKV][S][HD]
    float* __restrict__ outk,            // [NH][S][HD]
    float* __restrict__ outv,            // [NH][S][HD]
    unsigned short* __restrict__ vT)     // [NKV][HD][S]
{
  __shared__ float t[32][33];
  if (blockIdx.x < 2048) {
    const float QSCALE = 0.08838834764831845f * 1.4426950408889634f;
    int s = blockIdx.x;
    float pos = (float)positions[s];
    const unsigned short* r0 = &P0[(size_t)s * 3072];
    const unsigned short* r1 = &P1[(size_t)s * 3072];
    int tt = threadIdx.y * 32 + threadIdx.x;
    int j = tt & 63, grp = tt >> 6;
    float freq = expf(-(float)j * 0.14391156831212787f);  // ln(10000)/64
    float ang = pos * freq;
    float sn, c;
    sincosf(ang, &sn, &c);
    #pragma unroll
    for (int ci = 0; ci < 5; ci++) {
      int ch = grp * 5 + ci;                  // 0..19
      if (ch < NH) {
        int i1 = ch * HD + j, i2 = i1 + 64;
        float x1 = bf2f(r0[i1]) + bf2f(r1[i1]);
        float x2 = bf2f(r0[i2]) + bf2f(r1[i2]);
        float o1 = x1 * c - x2 * sn;
        float o2 = x1 * sn + x2 * c;
        size_t base = ((size_t)ch * S_LEN + s) * HD;
        q_ws[base + j] = f2bf(o1 * QSCALE);
        q_ws[base + j + 64] = f2bf(o2 * QSCALE);
      } else {
        int kv = ch - NH;
        int i1 = 2048 + kv * HD + j, i2 = i1 + 64;
        float x1 = bf2f(r0[i1]) + bf2f(r1[i1]);
        float x2 = bf2f(r0[i2]) + bf2f(r1[i2]);
        float o1 = x1 * c - x2 * sn;
        float o2 = x1 * sn + x2 * c;
        size_t kbase = ((size_t)kv * S_LEN + s) * HD;
        k_ws[kbase + j] = f2bf(o1);
        k_ws[kbase + j + 64] = f2bf(o2);
        #pragma unroll
        for (int g = 0; g < 4; g++) {
          size_t ob = ((size_t)(kv * 4 + g) * S_LEN + s) * HD;
          outk[ob + j] = o1;
          outk[ob + j + 64] = o2;
        }
      }
    }
  } else {
    int b = blockIdx.x - 2048;
    int s0 = (b & 63) * 32, d0 = ((b >> 6) & 3) * 32, kv = b >> 8;
    int tx = threadIdx.x & 31, ty = (threadIdx.y * 32 + threadIdx.x) >> 5;
    #pragma unroll
    for (int i = 0; i < 32; i += 8) {
      size_t idx = (size_t)(s0 + ty + i) * 3072 + 2560 + kv * HD + d0 + tx;
      t[ty + i][tx] = bf2f(P0[idx]) + bf2f(P1[idx]);
    }
    __syncthreads();
    #pragma unroll
    for (int i = 0; i < 32; i += 8) {
      float val = t[ty + i][tx];
      #pragma unroll
      for (int g = 0; g < 4; g++)
        outv[((size_t)(kv * 4 + g) * S_LEN + s0 + ty + i) * HD + d0 + tx] = val;
    }
    #pragma unroll
    for (int i = 0; i < 32; i += 8)
      vT[((size_t)kv * HD + d0 + ty + i) * S_LEN + s0 + tx] = f2bf(t[tx][ty + i]);
  }
}

// ---------------- staging helpers (async DMA, XOR-swizzled LDS) ----------------
__device__ inline void stage_k_tile(const unsigned short* kbase, unsigned short* dst,
                                    int wave, int lane) {
  #pragma unroll
  for (int i = 0; i < 4; i++) {
    int row = wave * 16 + i * 4 + (lane >> 4);
    int c = (lane & 15) ^ (row & 7);
    __builtin_amdgcn_global_load_lds(
        (const AS1 void*)(kbase + (size_t)row * HD + c * 8),
        (AS3 void*)(dst + (wave * 16 + i * 4) * 128),
        16, 0, 0);
  }
}

__device__ inline void stage_v_tile(const unsigned short* vbase, unsigned short* dst,
                                    int wave, int lane) {
  #pragma unroll
  for (int i = 0; i < 4; i++) {
    int row = wave * 32 + i * 8 + (lane >> 3);
    int c = (lane & 7) ^ (row & 7);
    __builtin_amdgcn_global_load_lds(
        (const AS1 void*)(vbase + (size_t)row * S_LEN + c * 8),
        (AS3 void*)(dst + (wave * 32 + i * 8) * 64),
        16, 0, 0);
  }
}

// ---------------- Flash attention v3 (exact 47.0 us version; 4 failed probes
// confirm this lockstep 2-barrier/8-wave-per-CU shape is the local optimum) ----
#define PLD 72
#define C2F 23.082320654223414f  // 16 * log2(e)

__global__ __launch_bounds__(256) void flash_attn3(
    const unsigned short* __restrict__ q_ws,
    const unsigned short* __restrict__ k_ws,
    const unsigned short* __restrict__ vT_ws,
    unsigned short* __restrict__ attn_ws)
{
  __shared__ __align__(16) unsigned short Ks[2][64 * 128];
  __shared__ __align__(16) unsigned short Vs[128 * 64];
  __shared__ __align__(16) unsigned short Ps[4][16 * PLD];
  const int b = blockIdx.x;
  const int u = b >> 4, h = b & 15, kvh = h >> 2;
  const int qt = (u < 16) ? (31 - u) : (u - 16);
  const int tid = threadIdx.x, lane = tid & 63, wave = tid >> 6;
  const int quad = lane >> 4, lcol = lane & 15;
  const int qrow = qt * 64 + wave * 16 + lcol;

  const unsigned short* kh = k_ws + (size_t)kvh * S_LEN * HD;
  const unsigned short* vh = vT_ws + (size_t)kvh * HD * S_LEN;

  bf16x8 qf[4];
  {
    const unsigned short* qp = &q_ws[((size_t)h * S_LEN + qrow) * HD + quad * 8];
    #pragma unroll
    for (int st = 0; st < 4; st++) qf[st] = *(const bf16x8*)&qp[st * 32];
  }
  f32x4 zero = {0.f, 0.f, 0.f, 0.f};
  f32x4 o_acc[8];
  #pragma unroll
  for (int i = 0; i < 8; i++) o_acc[i] = zero;
  float l_acc = 0.f;

  stage_k_tile(kh, &Ks[0][0], wave, lane);

  for (int kt = 0; kt <= qt; kt++) {
    int cur = kt & 1;
    __syncthreads();
    stage_v_tile(vh + kt * 64, &Vs[0], wave, lane);
    if (kt < qt) stage_k_tile(kh + (size_t)(kt + 1) * 64 * HD, &Ks[cur ^ 1][0], wave, lane);

    f32x4 sc[4];
    #pragma unroll
    for (int kb = 0; kb < 4; kb++) {
      sc[kb] = zero;
      #pragma unroll
      for (int st = 0; st < 4; st++) {
        int krow = kb * 16 + lcol;
        bf16x8 kf = *(const bf16x8*)&Ks[cur][krow * 128 + (((st * 4 + quad) ^ (lcol & 7)) * 8)];
        sc[kb] = __builtin_amdgcn_mfma_f32_16x16x32_bf16(kf, qf[st], sc[kb], 0, 0, 0);
      }
    }

    float pv[4][4];
    if (kt < qt) {
      #pragma unroll
      for (int kb = 0; kb < 4; kb++)
        #pragma unroll
        for (int r = 0; r < 4; r++) {
          float p = exp2f(sc[kb][r] - C2F);
          pv[kb][r] = p;
          l_acc += p;
        }
    } else {
      #pragma unroll
      for (int kb = 0; kb < 4; kb++)
        #pragma unroll
        for (int r = 0; r < 4; r++) {
          int key = kt * 64 + kb * 16 + quad * 4 + r;
          float p = (key <= qrow) ? exp2f(sc[kb][r] - C2F) : 0.f;
          pv[kb][r] = p;
          l_acc += p;
        }
    }

    unsigned short* myPs = &Ps[wave][0];
    #pragma unroll
    for (int kb = 0; kb < 4; kb++) {
      unsigned int u0 = (__float_as_uint(pv[kb][0]) + 0x8000u) >> 16;
      unsigned int u1 = (__float_as_uint(pv[kb][1]) + 0x8000u) & 0xFFFF0000u;
      unsigned int u2 = (__float_as_uint(pv[kb][2]) + 0x8000u) >> 16;
      unsigned int u3 = (__float_as_uint(pv[kb][3]) + 0x8000u) & 0xFFFF0000u;
      uint2 w2; w2.x = u0 | u1; w2.y = u2 | u3;
      *(uint2*)&myPs[lcol * PLD + kb * 16 + quad * 4] = w2;
    }
    __syncthreads();

    bf16x8 pa0 = *(const bf16x8*)&myPs[lcol * PLD + quad * 8];
    bf16x8 pa1 = *(const bf16x8*)&myPs[lcol * PLD + 32 + quad * 8];
    #pragma unroll
    for (int ob = 0; ob < 8; ob++) {
      int vrow = ob * 16 + lcol, sw = lcol & 7;
      bf16x8 v0 = *(const bf16x8*)&Vs[vrow * 64 + ((quad ^ sw) * 8)];
      bf16x8 v1 = *(const bf16x8*)&Vs[vrow * 64 + (((quad + 4) ^ sw) * 8)];
      o_acc[ob] = __builtin_amdgcn_mfma_f32_16x16x32_bf16(pa0, v0, o_acc[ob], 0, 0, 0);
      o_acc[ob] = __builtin_amdgcn_mfma_f32_16x16x32_bf16(pa1, v1, o_acc[ob], 0, 0, 0);
    }
  }

  float l = l_acc;
  l += __shfl_xor(l, 16);
  l += __shfl_xor(l, 32);
  float l_t[4];
  #pragma unroll
  for (int r = 0; r < 4; r++)
    l_t[r] = __shfl(l, (lane & 48) + quad * 4 + r);
  #pragma unroll
  for (int r = 0; r < 4; r++) {
    float inv = 1.f / l_t[r];
    int row = qt * 64 + wave * 16 + quad * 4 + r;
    #pragma unroll
    for (int ob = 0; ob < 8; ob++)
      attn_ws[(size_t)row * (NH * HD) + h * HD + ob * 16 + lcol] = f2bf(o_acc[ob][r] * inv);
  }
}

// ---------------- launch ----------------
extern "C" void kernel_launch(void* const* d_in, const int* in_sizes, int n_in,
                              void* d_out, int out_size, void* d_ws, size_t ws_size,
                              hipStream_t stream)
{
  const float* hidden    = (const float*)d_in[0];
  const int*   positions = (const int*)d_in[1];
  // d_in[2] = mask (causal triu(-1e9)) — implemented analytically
  const float* Wq = (const float*)d_in[3];
  const float* Wk = (const float*)d_in[4];
  const float* Wv = (const float*)d_in[5];
  const float* Wo = (const float*)d_in[6];

  float* out  = (float*)d_out;                       // [S][HID]
  float* outk = out + (size_t)S_LEN * HID_DIM;       // [NH][S][HD]
  float* outv = outk + (size_t)NH * S_LEN * HD;      // [NH][S][HD]

  char* ws = (char*)d_ws;
  unsigned short* h_bf   = (unsigned short*)(ws);                        // 0..8MB   [S][HID] bf16
  unsigned short* WT     = (unsigned short*)(ws + ((size_t)8  << 20));   // 8..20MB  [3072][2048] bf16
  unsigned short* WoT    = (unsigned short*)(ws + ((size_t)20 << 20));   // 20..28MB [2048][2048] bf16
  unsigned short* qkvP   = (unsigned short*)(ws + ((size_t)28 << 20));   // 28..52MB [2][S][3072] bf16 partials
  unsigned short* q_ws   = (unsigned short*)(ws + ((size_t)52 << 20));   // 52..60MB
  unsigned short* k_ws   = (unsigned short*)(ws + ((size_t)60 << 20));   // 60..62MB
  unsigned short* vT_ws  = (unsigned short*)(ws + ((size_t)62 << 20));   // 62..64MB
  unsigned short* attn   = (unsigned short*)(ws + ((size_t)64 << 20));   // 64..72MB [S][NH*HD] bf16
  unsigned short* qkvP1  = qkvP + (size_t)S_LEN * 3072;

  // zero the f32 output region (16.8 MB) for the fused atomic out-proj epilogue;
  // outk/outv regions are fully overwritten by rope_prepv, no memset needed.
  hipMemsetAsync(out, 0, (size_t)S_LEN * HID_DIM * sizeof(float), stream);

  transpose_all<<<dim3(64, 64, 5), dim3(32, 8), 0, stream>>>(
      Wq, Wk, Wv, Wo, WT, WoT, hidden, h_bf);

  // QKV GEMM: M=2048, N=3072, KF=2048, split-K=2, 256^2 8-phase -> 192 blocks
  gemm_bt_8phase<<<dim3(12, 8, 2), 512, 131072, stream>>>(
      h_bf, WT, qkvP, nullptr, 2048, 3072, 2048, 2);

  // fused RoPE (blocks 0..2047) + V-prep (blocks 2048..3071)
  rope_prepv_kernel<<<3072, 256, 0, stream>>>(qkvP, qkvP1, positions,
                                              q_ws, k_ws, outk, outv, vT_ws);

  flash_attn3<<<dim3(512), 256, 0, stream>>>(q_ws, k_ws, vT_ws, attn);

  // out-proj GEMM: M=2048, N=2048, KF=2048, split-K=4 -> 256 blocks (1/CU),
  // fused f32 atomic accumulation into pre-zeroed out (no add pass)
  gemm_bt_8phase<<<dim3(8, 8, 4), 512, 131072, stream>>>(
      attn, WoT, nullptr, out, 2048, 2048, 2048, 4);
}

// Round 12
// 237.011 us; speedup vs baseline: 1.2076x; 1.2076x over previous
//
#include <hip/hip_runtime.h>
#include <hip/hip_bf16.h>
#include <math.h>

#define S_LEN 2048
#define HID_DIM 2048
#define NH 16
#define NKV 4
#define HD 128

typedef __attribute__((ext_vector_type(8))) short bf16x8;
typedef __attribute__((ext_vector_type(4))) float f32x4;

#define AS1 __attribute__((address_space(1)))
#define AS3 __attribute__((address_space(3)))

__device__ inline unsigned short f2bf(float f) {
  unsigned int u = __float_as_uint(f);
  unsigned int r = u + 0x7FFFu + ((u >> 16) & 1u);
  return (unsigned short)(r >> 16);
}
__device__ inline float bf2f(unsigned short u) {
  return __uint_as_float(((unsigned int)u) << 16);
}

// ---------------- weight transposes + hidden f32->bf16, one dispatch ----------
// z=0..3: transpose Wq/Wk/Wv/Wo into WT/WoT. z=4: hidden f32 -> bf16 copy.
__global__ __launch_bounds__(256) void transpose_all(
    const float* __restrict__ Wq, const float* __restrict__ Wk,
    const float* __restrict__ Wv, const float* __restrict__ Wo,
    unsigned short* __restrict__ WT, unsigned short* __restrict__ WoT,
    const float* __restrict__ hidden, unsigned short* __restrict__ h_bf)
{
  const int z = blockIdx.z;
  if (z == 4) {
    int bb = blockIdx.y * 64 + blockIdx.x;           // 0..4095
    int t = threadIdx.y * 32 + threadIdx.x;          // 0..255
    int i = (bb * 256 + t) * 4;
    float4 v = *(const float4*)&hidden[i];
    ushort4 o;
    o.x = f2bf(v.x); o.y = f2bf(v.y); o.z = f2bf(v.z); o.w = f2bf(v.w);
    *(ushort4*)&h_bf[i] = o;
    return;
  }
  __shared__ float t[32][33];
  const float* W; unsigned short* D; int N;
  if (z == 0)      { W = Wq; D = WT;                          N = 2048; }
  else if (z == 1) { W = Wk; D = WT + (size_t)2048 * 2048;    N = 512;  }
  else if (z == 2) { W = Wv; D = WT + (size_t)2560 * 2048;    N = 512;  }
  else             { W = Wo; D = WoT;                         N = 2048; }
  int bx = blockIdx.x * 32;
  if (bx >= N) return;
  int by = blockIdx.y * 32;
  int tx = threadIdx.x, ty = threadIdx.y;
  #pragma unroll
  for (int i = 0; i < 32; i += 8)
    t[ty + i][tx] = W[(size_t)(by + ty + i) * N + bx + tx];
  __syncthreads();
  #pragma unroll
  for (int i = 0; i < 32; i += 8)
    D[(size_t)(bx + ty + i) * 2048 + by + tx] = f2bf(t[tx][ty + i]);
}

// ---------------- 256x256 8-phase split-K GEMM (T3+T4+T5 template) ----------
__global__ __launch_bounds__(512) void gemm_bt_8phase(
    const unsigned short* __restrict__ A,
    const unsigned short* __restrict__ Bt,
    unsigned short* __restrict__ P,   // [ksplit][M][N] bf16 partials
    int M, int N, int KF, int ksplit)
{
  extern __shared__ unsigned short smem[];
  unsigned short* Ab = smem;            // [2 buf][2 kh][256*32] = 32768 ush
  unsigned short* Bb = smem + 32768;    // same
  const int bm = blockIdx.y * 256, bn = blockIdx.x * 256, z = blockIdx.z;
  const int Kh = KF / ksplit, k0z = z * Kh;
  const int NT = Kh >> 6;               // K-tiles of 64
  const int tid = threadIdx.x, lane = tid & 63, wave = tid >> 6;
  const int wm = wave >> 2, wn = wave & 3;
  const int quad = lane >> 4, lcol = lane & 15;

  auto stageA = [&](int t, int kh) {
    const unsigned short* src = A + (size_t)bm * KF + k0z + t * 64 + kh * 32;
    unsigned short* dst = Ab + (((t & 1) * 2 + kh) << 13);
    #pragma unroll
    for (int i = 0; i < 2; i++) {
      int s = i * 512 + tid;
      int row = s >> 2, dc = s & 3, g = dc ^ ((row >> 1) & 3);
      __builtin_amdgcn_global_load_lds(
          (const AS1 void*)(src + (size_t)row * KF + g * 8),
          (AS3 void*)(dst + s * 8), 16, 0, 0);
    }
  };
  auto stageB = [&](int t, int kh) {
    const unsigned short* src = Bt + (size_t)bn * KF + k0z + t * 64 + kh * 32;
    unsigned short* dst = Bb + (((t & 1) * 2 + kh) << 13);
    #pragma unroll
    for (int i = 0; i < 2; i++) {
      int s = i * 512 + tid;
      int row = s >> 2, dc = s & 3, g = dc ^ ((row >> 1) & 3);
      __builtin_amdgcn_global_load_lds(
          (const AS1 void*)(src + (size_t)row * KF + g * 8),
          (AS3 void*)(dst + s * 8), 16, 0, 0);
    }
  };
  auto ldA = [&](int cur, int kh, int mh, bf16x8* af) {
    const unsigned short* base = Ab + ((cur * 2 + kh) << 13);
    #pragma unroll
    for (int m = 0; m < 4; m++) {
      int row = wm * 128 + (mh * 4 + m) * 16 + lcol;
      int ch = quad ^ ((row >> 1) & 3);
      af[m] = *(const bf16x8*)&base[row * 32 + ch * 8];
    }
  };
  auto ldB = [&](int cur, int kh, bf16x8* bfr) {
    const unsigned short* base = Bb + ((cur * 2 + kh) << 13);
    #pragma unroll
    for (int n = 0; n < 4; n++) {
      int row = wn * 64 + n * 16 + lcol;
      int ch = quad ^ ((row >> 1) & 3);
      bfr[n] = *(const bf16x8*)&base[row * 32 + ch * 8];
    }
  };

  f32x4 zero = {0.f, 0.f, 0.f, 0.f};
  f32x4 acc[8][4];
  #pragma unroll
  for (int i = 0; i < 8; i++)
    #pragma unroll
    for (int j = 0; j < 4; j++) acc[i][j] = zero;

  stageA(0, 0); stageB(0, 0); stageA(0, 1); stageB(0, 1);
  if (NT > 1) { stageA(1, 0); stageB(1, 0); }
  asm volatile("s_waitcnt vmcnt(8)" ::: "memory");
  __builtin_amdgcn_s_barrier();

  for (int t = 0; t < NT; t++) {
    const int cur = t & 1;
    bf16x8 af[4], bfr[4];
    // ---- p0: kh0, mh0 ----
    ldB(cur, 0, bfr);
    ldA(cur, 0, 0, af);
    __builtin_amdgcn_s_barrier();
    if (t + 1 < NT) stageA(t + 1, 1);
    __builtin_amdgcn_s_setprio(1);
    #pragma unroll
    for (int m = 0; m < 4; m++)
      #pragma unroll
      for (int n = 0; n < 4; n++)
        acc[m][n] = __builtin_amdgcn_mfma_f32_16x16x32_bf16(af[m], bfr[n], acc[m][n], 0, 0, 0);
    __builtin_amdgcn_s_setprio(0);
    // ---- p1: kh0, mh1 ----
    ldA(cur, 0, 1, af);
    asm volatile("s_waitcnt vmcnt(6)" ::: "memory");
    __builtin_amdgcn_s_barrier();
    if (t + 1 < NT) stageB(t + 1, 1);
    __builtin_amdgcn_s_setprio(1);
    #pragma unroll
    for (int m = 0; m < 4; m++)
      #pragma unroll
      for (int n = 0; n < 4; n++)
        acc[4 + m][n] = __builtin_amdgcn_mfma_f32_16x16x32_bf16(af[m], bfr[n], acc[4 + m][n], 0, 0, 0);
    __builtin_amdgcn_s_setprio(0);
    // ---- p2: kh1, mh0 ----
    ldB(cur, 1, bfr);
    ldA(cur, 1, 0, af);
    __builtin_amdgcn_s_barrier();
    if (t + 2 < NT) stageA(t + 2, 0);
    __builtin_amdgcn_s_setprio(1);
    #pragma unroll
    for (int m = 0; m < 4; m++)
      #pragma unroll
      for (int n = 0; n < 4; n++)
        acc[m][n] = __builtin_amdgcn_mfma_f32_16x16x32_bf16(af[m], bfr[n], acc[m][n], 0, 0, 0);
    __builtin_amdgcn_s_setprio(0);
    // ---- p3: kh1, mh1 ----
    ldA(cur, 1, 1, af);
    asm volatile("s_waitcnt vmcnt(6)" ::: "memory");
    __builtin_amdgcn_s_barrier();
    if (t + 2 < NT) stageB(t + 2, 0);
    __builtin_amdgcn_s_setprio(1);
    #pragma unroll
    for (int m = 0; m < 4; m++)
      #pragma unroll
      for (int n = 0; n < 4; n++)
        acc[4 + m][n] = __builtin_amdgcn_mfma_f32_16x16x32_bf16(af[m], bfr[n], acc[4 + m][n], 0, 0, 0);
    __builtin_amdgcn_s_setprio(0);
  }

  unsigned short* Pz = P + (size_t)z * M * N;
  #pragma unroll
  for (int mr = 0; mr < 8; mr++)
    #pragma unroll
    for (int nr = 0; nr < 4; nr++)
      #pragma unroll
      for (int r = 0; r < 4; r++) {
        int mm = bm + wm * 128 + mr * 16 + quad * 4 + r;
        int nn = bn + wn * 64 + nr * 16 + lcol;
        Pz[(size_t)mm * N + nn] = f2bf(acc[mr][nr][r]);
      }
}

// ---------------- final add: out = P0+P1+P2+P3 (bf16 -> f32) ----------------
__global__ __launch_bounds__(256) void add_out4_kernel(
    const unsigned short* __restrict__ P0, const unsigned short* __restrict__ P1,
    const unsigned short* __restrict__ P2, const unsigned short* __restrict__ P3,
    float* __restrict__ out, int n)
{
  int i = (blockIdx.x * 256 + threadIdx.x) * 8;
  if (i < n) {
    uint4 a = *(const uint4*)&P0[i];
    uint4 b = *(const uint4*)&P1[i];
    uint4 c = *(const uint4*)&P2[i];
    uint4 d = *(const uint4*)&P3[i];
    float o[8];
    o[0] = __uint_as_float(a.x << 16) + __uint_as_float(b.x << 16)
         + __uint_as_float(c.x << 16) + __uint_as_float(d.x << 16);
    o[1] = __uint_as_float(a.x & 0xFFFF0000u) + __uint_as_float(b.x & 0xFFFF0000u)
         + __uint_as_float(c.x & 0xFFFF0000u) + __uint_as_float(d.x & 0xFFFF0000u);
    o[2] = __uint_as_float(a.y << 16) + __uint_as_float(b.y << 16)
         + __uint_as_float(c.y << 16) + __uint_as_float(d.y << 16);
    o[3] = __uint_as_float(a.y & 0xFFFF0000u) + __uint_as_float(b.y & 0xFFFF0000u)
         + __uint_as_float(c.y & 0xFFFF0000u) + __uint_as_float(d.y & 0xFFFF0000u);
    o[4] = __uint_as_float(a.z << 16) + __uint_as_float(b.z << 16)
         + __uint_as_float(c.z << 16) + __uint_as_float(d.z << 16);
    o[5] = __uint_as_float(a.z & 0xFFFF0000u) + __uint_as_float(b.z & 0xFFFF0000u)
         + __uint_as_float(c.z & 0xFFFF0000u) + __uint_as_float(d.z & 0xFFFF0000u);
    o[6] = __uint_as_float(a.w << 16) + __uint_as_float(b.w << 16)
         + __uint_as_float(c.w << 16) + __uint_as_float(d.w << 16);
    o[7] = __uint_as_float(a.w & 0xFFFF0000u) + __uint_as_float(b.w & 0xFFFF0000u)
         + __uint_as_float(c.w & 0xFFFF0000u) + __uint_as_float(d.w & 0xFFFF0000u);
    *(float4*)&out[i] = *(float4*)&o[0];
    *(float4*)&out[i + 4] = *(float4*)&o[4];
  }
}

// ---------------- fused RoPE + V-prep (one dispatch) ----------------
__global__ __launch_bounds__(256) void rope_prepv_kernel(
    const unsigned short* __restrict__ P0,  // [S][3072] bf16
    const unsigned short* __restrict__ P1,
    const int* __restrict__ positions,
    unsigned short* __restrict__ q_ws,   // [NH][S][HD]  (scaled!)
    unsigned short* __restrict__ k_ws,   // [NKV][S][HD]
    float* __restrict__ outk,            // [NH][S][HD]
    float* __restrict__ outv,            // [NH][S][HD]
    unsigned short* __restrict__ vT)     // [NKV][HD][S]
{
  __shared__ float t[32][33];
  if (blockIdx.x < 2048) {
    const float QSCALE = 0.08838834764831845f * 1.4426950408889634f;
    int s = blockIdx.x;
    float pos = (float)positions[s];
    const unsigned short* r0 = &P0[(size_t)s * 3072];
    const unsigned short* r1 = &P1[(size_t)s * 3072];
    int tt = threadIdx.y * 32 + threadIdx.x;
    int j = tt & 63, grp = tt >> 6;
    float freq = expf(-(float)j * 0.14391156831212787f);  // ln(10000)/64
    float ang = pos * freq;
    float sn, c;
    sincosf(ang, &sn, &c);
    #pragma unroll
    for (int ci = 0; ci < 5; ci++) {
      int ch = grp * 5 + ci;                  // 0..19
      if (ch < NH) {
        int i1 = ch * HD + j, i2 = i1 + 64;
        float x1 = bf2f(r0[i1]) + bf2f(r1[i1]);
        float x2 = bf2f(r0[i2]) + bf2f(r1[i2]);
        float o1 = x1 * c - x2 * sn;
        float o2 = x1 * sn + x2 * c;
        size_t base = ((size_t)ch * S_LEN + s) * HD;
        q_ws[base + j] = f2bf(o1 * QSCALE);
        q_ws[base + j + 64] = f2bf(o2 * QSCALE);
      } else {
        int kv = ch - NH;
        int i1 = 2048 + kv * HD + j, i2 = i1 + 64;
        float x1 = bf2f(r0[i1]) + bf2f(r1[i1]);
        float x2 = bf2f(r0[i2]) + bf2f(r1[i2]);
        float o1 = x1 * c - x2 * sn;
        float o2 = x1 * sn + x2 * c;
        size_t kbase = ((size_t)kv * S_LEN + s) * HD;
        k_ws[kbase + j] = f2bf(o1);
        k_ws[kbase + j + 64] = f2bf(o2);
        #pragma unroll
        for (int g = 0; g < 4; g++) {
          size_t ob = ((size_t)(kv * 4 + g) * S_LEN + s) * HD;
          outk[ob + j] = o1;
          outk[ob + j + 64] = o2;
        }
      }
    }
  } else {
    int b = blockIdx.x - 2048;
    int s0 = (b & 63) * 32, d0 = ((b >> 6) & 3) * 32, kv = b >> 8;
    int tx = threadIdx.x & 31, ty = (threadIdx.y * 32 + threadIdx.x) >> 5;
    #pragma unroll
    for (int i = 0; i < 32; i += 8) {
      size_t idx = (size_t)(s0 + ty + i) * 3072 + 2560 + kv * HD + d0 + tx;
      t[ty + i][tx] = bf2f(P0[idx]) + bf2f(P1[idx]);
    }
    __syncthreads();
    #pragma unroll
    for (int i = 0; i < 32; i += 8) {
      float val = t[ty + i][tx];
      #pragma unroll
      for (int g = 0; g < 4; g++)
        outv[((size_t)(kv * 4 + g) * S_LEN + s0 + ty + i) * HD + d0 + tx] = val;
    }
    #pragma unroll
    for (int i = 0; i < 32; i += 8)
      vT[((size_t)kv * HD + d0 + ty + i) * S_LEN + s0 + tx] = f2bf(t[tx][ty + i]);
  }
}

// ---------------- staging helpers (async DMA, XOR-swizzled LDS) ----------------
__device__ inline void stage_k_tile(const unsigned short* kbase, unsigned short* dst,
                                    int wave, int lane) {
  #pragma unroll
  for (int i = 0; i < 4; i++) {
    int row = wave * 16 + i * 4 + (lane >> 4);
    int c = (lane & 15) ^ (row & 7);
    __builtin_amdgcn_global_load_lds(
        (const AS1 void*)(kbase + (size_t)row * HD + c * 8),
        (AS3 void*)(dst + (wave * 16 + i * 4) * 128),
        16, 0, 0);
  }
}

__device__ inline void stage_v_tile(const unsigned short* vbase, unsigned short* dst,
                                    int wave, int lane) {
  #pragma unroll
  for (int i = 0; i < 4; i++) {
    int row = wave * 32 + i * 8 + (lane >> 3);
    int c = (lane & 7) ^ (row & 7);
    __builtin_amdgcn_global_load_lds(
        (const AS1 void*)(vbase + (size_t)row * S_LEN + c * 8),
        (AS3 void*)(dst + (wave * 32 + i * 8) * 64),
        16, 0, 0);
  }
}

// ---------------- Flash attention v3 (exact 47.0 us version; 4 failed probes
// confirm this lockstep 2-barrier/8-wave-per-CU shape is the local optimum) ----
#define PLD 72
#define C2F 23.082320654223414f  // 16 * log2(e)

__global__ __launch_bounds__(256) void flash_attn3(
    const unsigned short* __restrict__ q_ws,
    const unsigned short* __restrict__ k_ws,
    const unsigned short* __restrict__ vT_ws,
    unsigned short* __restrict__ attn_ws)
{
  __shared__ __align__(16) unsigned short Ks[2][64 * 128];
  __shared__ __align__(16) unsigned short Vs[128 * 64];
  __shared__ __align__(16) unsigned short Ps[4][16 * PLD];
  const int b = blockIdx.x;
  const int u = b >> 4, h = b & 15, kvh = h >> 2;
  const int qt = (u < 16) ? (31 - u) : (u - 16);
  const int tid = threadIdx.x, lane = tid & 63, wave = tid >> 6;
  const int quad = lane >> 4, lcol = lane & 15;
  const int qrow = qt * 64 + wave * 16 + lcol;

  const unsigned short* kh = k_ws + (size_t)kvh * S_LEN * HD;
  const unsigned short* vh = vT_ws + (size_t)kvh * HD * S_LEN;

  bf16x8 qf[4];
  {
    const unsigned short* qp = &q_ws[((size_t)h * S_LEN + qrow) * HD + quad * 8];
    #pragma unroll
    for (int st = 0; st < 4; st++) qf[st] = *(const bf16x8*)&qp[st * 32];
  }
  f32x4 zero = {0.f, 0.f, 0.f, 0.f};
  f32x4 o_acc[8];
  #pragma unroll
  for (int i = 0; i < 8; i++) o_acc[i] = zero;
  float l_acc = 0.f;

  stage_k_tile(kh, &Ks[0][0], wave, lane);

  for (int kt = 0; kt <= qt; kt++) {
    int cur = kt & 1;
    __syncthreads();
    stage_v_tile(vh + kt * 64, &Vs[0], wave, lane);
    if (kt < qt) stage_k_tile(kh + (size_t)(kt + 1) * 64 * HD, &Ks[cur ^ 1][0], wave, lane);

    f32x4 sc[4];
    #pragma unroll
    for (int kb = 0; kb < 4; kb++) {
      sc[kb] = zero;
      #pragma unroll
      for (int st = 0; st < 4; st++) {
        int krow = kb * 16 + lcol;
        bf16x8 kf = *(const bf16x8*)&Ks[cur][krow * 128 + (((st * 4 + quad) ^ (lcol & 7)) * 8)];
        sc[kb] = __builtin_amdgcn_mfma_f32_16x16x32_bf16(kf, qf[st], sc[kb], 0, 0, 0);
      }
    }

    float pv[4][4];
    if (kt < qt) {
      #pragma unroll
      for (int kb = 0; kb < 4; kb++)
        #pragma unroll
        for (int r = 0; r < 4; r++) {
          float p = exp2f(sc[kb][r] - C2F);
          pv[kb][r] = p;
          l_acc += p;
        }
    } else {
      #pragma unroll
      for (int kb = 0; kb < 4; kb++)
        #pragma unroll
        for (int r = 0; r < 4; r++) {
          int key = kt * 64 + kb * 16 + quad * 4 + r;
          float p = (key <= qrow) ? exp2f(sc[kb][r] - C2F) : 0.f;
          pv[kb][r] = p;
          l_acc += p;
        }
    }

    unsigned short* myPs = &Ps[wave][0];
    #pragma unroll
    for (int kb = 0; kb < 4; kb++) {
      unsigned int u0 = (__float_as_uint(pv[kb][0]) + 0x8000u) >> 16;
      unsigned int u1 = (__float_as_uint(pv[kb][1]) + 0x8000u) & 0xFFFF0000u;
      unsigned int u2 = (__float_as_uint(pv[kb][2]) + 0x8000u) >> 16;
      unsigned int u3 = (__float_as_uint(pv[kb][3]) + 0x8000u) & 0xFFFF0000u;
      uint2 w2; w2.x = u0 | u1; w2.y = u2 | u3;
      *(uint2*)&myPs[lcol * PLD + kb * 16 + quad * 4] = w2;
    }
    __syncthreads();

    bf16x8 pa0 = *(const bf16x8*)&myPs[lcol * PLD + quad * 8];
    bf16x8 pa1 = *(const bf16x8*)&myPs[lcol * PLD + 32 + quad * 8];
    #pragma unroll
    for (int ob = 0; ob < 8; ob++) {
      int vrow = ob * 16 + lcol, sw = lcol & 7;
      bf16x8 v0 = *(const bf16x8*)&Vs[vrow * 64 + ((quad ^ sw) * 8)];
      bf16x8 v1 = *(const bf16x8*)&Vs[vrow * 64 + (((quad + 4) ^ sw) * 8)];
      o_acc[ob] = __builtin_amdgcn_mfma_f32_16x16x32_bf16(pa0, v0, o_acc[ob], 0, 0, 0);
      o_acc[ob] = __builtin_amdgcn_mfma_f32_16x16x32_bf16(pa1, v1, o_acc[ob], 0, 0, 0);
    }
  }

  float l = l_acc;
  l += __shfl_xor(l, 16);
  l += __shfl_xor(l, 32);
  float l_t[4];
  #pragma unroll
  for (int r = 0; r < 4; r++)
    l_t[r] = __shfl(l, (lane & 48) + quad * 4 + r);
  #pragma unroll
  for (int r = 0; r < 4; r++) {
    float inv = 1.f / l_t[r];
    int row = qt * 64 + wave * 16 + quad * 4 + r;
    #pragma unroll
    for (int ob = 0; ob < 8; ob++)
      attn_ws[(size_t)row * (NH * HD) + h * HD + ob * 16 + lcol] = f2bf(o_acc[ob][r] * inv);
  }
}

// ---------------- launch ----------------
extern "C" void kernel_launch(void* const* d_in, const int* in_sizes, int n_in,
                              void* d_out, int out_size, void* d_ws, size_t ws_size,
                              hipStream_t stream)
{
  const float* hidden    = (const float*)d_in[0];
  const int*   positions = (const int*)d_in[1];
  // d_in[2] = mask (causal triu(-1e9)) — implemented analytically
  const float* Wq = (const float*)d_in[3];
  const float* Wk = (const float*)d_in[4];
  const float* Wv = (const float*)d_in[5];
  const float* Wo = (const float*)d_in[6];

  float* out  = (float*)d_out;                       // [S][HID]
  float* outk = out + (size_t)S_LEN * HID_DIM;       // [NH][S][HD]
  float* outv = outk + (size_t)NH * S_LEN * HD;      // [NH][S][HD]

  char* ws = (char*)d_ws;
  unsigned short* h_bf   = (unsigned short*)(ws);                        // 0..8MB   [S][HID] bf16
  unsigned short* WT     = (unsigned short*)(ws + ((size_t)8  << 20));   // 8..20MB  [3072][2048] bf16
  unsigned short* WoT    = (unsigned short*)(ws + ((size_t)20 << 20));   // 20..28MB [2048][2048] bf16
  unsigned short* qkvP   = (unsigned short*)(ws + ((size_t)28 << 20));   // 28..52MB [2][S][3072] bf16 partials
  unsigned short* q_ws   = (unsigned short*)(ws + ((size_t)52 << 20));   // 52..60MB
  unsigned short* k_ws   = (unsigned short*)(ws + ((size_t)60 << 20));   // 60..62MB
  unsigned short* vT_ws  = (unsigned short*)(ws + ((size_t)62 << 20));   // 62..64MB
  unsigned short* attn   = (unsigned short*)(ws + ((size_t)64 << 20));   // 64..72MB [S][NH*HD] bf16
  unsigned short* qkvP1  = qkvP + (size_t)S_LEN * 3072;
  // out-proj partials: [4][2048][2048] bf16 = 32MB at 28..60MB; qkvP, q_ws,
  // k_ws are all dead by the out-proj GEMM (flash done). vT/attn untouched.
  unsigned short* outP   = qkvP;
  const size_t OPE = (size_t)2048 * 2048;

  transpose_all<<<dim3(64, 64, 5), dim3(32, 8), 0, stream>>>(
      Wq, Wk, Wv, Wo, WT, WoT, hidden, h_bf);

  // QKV GEMM: M=2048, N=3072, KF=2048, split-K=2, 256^2 8-phase -> 192 blocks
  gemm_bt_8phase<<<dim3(12, 8, 2), 512, 131072, stream>>>(h_bf, WT, qkvP, 2048, 3072, 2048, 2);

  // fused RoPE (blocks 0..2047) + V-prep (blocks 2048..3071)
  rope_prepv_kernel<<<3072, 256, 0, stream>>>(qkvP, qkvP1, positions,
                                              q_ws, k_ws, outk, outv, vT_ws);

  flash_attn3<<<dim3(512), 256, 0, stream>>>(q_ws, k_ws, vT_ws, attn);

  // out-proj GEMM: M=2048, N=2048, KF=2048, split-K=4 -> 256 blocks (1/CU)
  gemm_bt_8phase<<<dim3(8, 8, 4), 512, 131072, stream>>>(attn, WoT, outP, 2048, 2048, 2048, 4);
  add_out4_kernel<<<2048, 256, 0, stream>>>(outP, outP + OPE, outP + 2 * OPE, outP + 3 * OPE,
                                            out, S_LEN * HID_DIM);
}